// Round 14
// baseline (1323.743 us; speedup 1.0000x reference)
//
#include <hip/hip_runtime.h>
#include <math.h>

#define BATCH 65536
#define KIN   784
#define HD    768

typedef float f32x4 __attribute__((ext_vector_type(4)));
typedef short s16x8 __attribute__((ext_vector_type(8)));
typedef unsigned int __attribute__((address_space(3))) lds_u32;
typedef const unsigned int __attribute__((address_space(1))) glb_u32;

__device__ __forceinline__ float frelu(float x){ return x > 0.f ? x : 0.f; }

// packed bf16 convert: dst = {lo16=cvt(a), hi16=cvt(b)}
__device__ __forceinline__ unsigned int cvtpk(float a, float b){
    unsigned int r;
    asm("v_cvt_pk_bf16_f32 %0, %1, %2" : "=v"(r) : "v"(a), "v"(b));
    return r;
}
__device__ __forceinline__ unsigned short f2bf(float v){
    unsigned int u = __builtin_bit_cast(unsigned int, v);
    u += 0x7FFFu + ((u >> 16) & 1u);
    return (unsigned short)(u >> 16);
}
__device__ __forceinline__ float bf2f(unsigned short s){
    unsigned int u = ((unsigned int)s) << 16;
    return __builtin_bit_cast(float, u);
}
__device__ __forceinline__ void gload16(const void* g, void* l){
    __builtin_amdgcn_global_load_lds((glb_u32*)g, (lds_u32*)l, 16, 0, 0);
}

// ---------------------------------------------------------------------------
// x [B,784] fp32 -> xbf [B,800] bf16 (pad zeroed). One uint4 (8 elems)/thread.
// ---------------------------------------------------------------------------
__global__ __launch_bounds__(256)
void cvtX(const float* __restrict__ x, unsigned short* __restrict__ xbf)
{
    int idx = blockIdx.x * 256 + threadIdx.x;     // BATCH*100 total
    int row = idx / 100, c = (idx - row * 100) * 8;
    uint4 o = make_uint4(0, 0, 0, 0);
    if (c < KIN) {
        const float* p = x + (size_t)row * KIN + c;
        float4 a = *(const float4*)p;
        float4 b = *(const float4*)(p + 4);
        o.x = cvtpk(a.x, a.y); o.y = cvtpk(a.z, a.w);
        o.z = cvtpk(b.x, b.y); o.w = cvtpk(b.z, b.w);
    }
    *(uint4*)(xbf + (size_t)row * 800 + c) = o;
}

// ---------------------------------------------------------------------------
// feat = relu(hbf*scale + shift) -> fbf (bf16). 8 elems/thread.
// ---------------------------------------------------------------------------
__global__ __launch_bounds__(256)
void featBN(const unsigned short* __restrict__ hbf,
            const float* __restrict__ scale, const float* __restrict__ shift,
            unsigned short* __restrict__ fbf)
{
    int idx = blockIdx.x * 256 + threadIdx.x;     // BATCH*96 total
    int row = idx / 96, c = (idx - row * 96) * 8;
    s16x8 hv = *(const s16x8*)(hbf + (size_t)row * HD + c);
    float4 s0 = *(const float4*)(scale + c), s1 = *(const float4*)(scale + c + 4);
    float4 t0 = *(const float4*)(shift + c), t1 = *(const float4*)(shift + c + 4);
    float v[8];
    v[0] = frelu(bf2f((unsigned short)hv[0]) * s0.x + t0.x);
    v[1] = frelu(bf2f((unsigned short)hv[1]) * s0.y + t0.y);
    v[2] = frelu(bf2f((unsigned short)hv[2]) * s0.z + t0.z);
    v[3] = frelu(bf2f((unsigned short)hv[3]) * s0.w + t0.w);
    v[4] = frelu(bf2f((unsigned short)hv[4]) * s1.x + t1.x);
    v[5] = frelu(bf2f((unsigned short)hv[5]) * s1.y + t1.y);
    v[6] = frelu(bf2f((unsigned short)hv[6]) * s1.z + t1.z);
    v[7] = frelu(bf2f((unsigned short)hv[7]) * s1.w + t1.w);
    uint4 o;
    o.x = cvtpk(v[0], v[1]); o.y = cvtpk(v[2], v[3]);
    o.z = cvtpk(v[4], v[5]); o.w = cvtpk(v[6], v[7]);
    *(uint4*)(fbf + (size_t)row * HD + c) = o;
}

// ---------------------------------------------------------------------------
// Pre-tile W[K][N] fp32 -> bf16 per-(nb,t) 8KB chunks = exact swizzled LDS
// image: byte (r*64+p*16+e*2) = bf16 of W[t*32+s*8+e][nb*128+r], s=p^((r>>1)&3)
// ---------------------------------------------------------------------------
__global__ __launch_bounds__(256)
void tileW(const float* __restrict__ W, char* __restrict__ Wh, int K, int N, int NT)
{
    int chunk = blockIdx.x;
    int nb = chunk / NT, t = chunk - nb * NT;
    int tid = threadIdx.x;
    #pragma unroll
    for (int q = 0; q < 2; q++) {
        int idx = q * 256 + tid;
        int r = idx >> 2, p = idx & 3;
        int s = (p ^ ((r >> 1) & 3)) & 3;
        int kb = t * 32 + s * 8;
        int n = nb * 128 + r;
        s16x8 hv;
        #pragma unroll
        for (int e = 0; e < 8; e++) {
            int k = kb + e;
            float v = (k < K) ? W[(size_t)k * N + n] : 0.f;
            hv[e] = (short)f2bf(v);
        }
        *(s16x8*)(Wh + (size_t)chunk * 8192 + idx * 16) = hv;
    }
}

// ---------------------------------------------------------------------------
// m97-shaped bf16 GEMM: BOTH operands staged via global_load_lds (A from a
// bf16 row-major array with per-lane pre-swizzled k-offsets; B from pre-tiled
// chunks). ZERO VALU in the K-loop. Single 16KB buffer, 2-barrier loop.
// MODE 0: A=xbf(KP=800); epilogue h(bf16) + fused BN column partials.
// MODE 1: A=fbf(KP=768); epilogue a=relu(acc+bd1); domacc += a @ Wd2.
// ---------------------------------------------------------------------------
template<int MODE>
__global__ __launch_bounds__(256, 3)
void gemm97(const unsigned short* __restrict__ Abf,
            const char* __restrict__ BhC,
            const float* __restrict__ bias,
            unsigned short* __restrict__ Hbf,
            const float* __restrict__ Wd2, double* __restrict__ domacc,
            float* __restrict__ sp1, float* __restrict__ sp2,
            int KP, int NT)
{
    __shared__ __align__(16) char sm[16384];      // A 8KB | B 8KB

    int bid = blockIdx.x;
    int wg = (bid & 7) * 384 + (bid >> 3);        // XCD-contiguous remap
    int mb = wg / 6, nb = wg - mb * 6;
    int m0 = mb << 7, n0 = nb << 7;

    int tid = threadIdx.x;
    int lane = tid & 63, wid = tid >> 6;
    int wr = wid >> 1, wc = wid & 1;
    int l15 = lane & 15, l4 = lane >> 4;

    int aoff[4], boff[4];
    #pragma unroll
    for (int f = 0; f < 4; f++) {
        int ra = wr * 64 + f * 16 + l15;
        aoff[f] = ra * 64 + (((l4 ^ (ra >> 1)) & 3) << 4);
        int rb = wc * 64 + f * 16 + l15;
        boff[f] = rb * 64 + (((l4 ^ (rb >> 1)) & 3) << 4);
    }

    // staging: idx = q*256+tid -> row r, phys slot p; source k-group s
    int ar[2], asl[2];
    #pragma unroll
    for (int q = 0; q < 2; q++) {
        int idx = q * 256 + tid;
        int r = idx >> 2, p = idx & 3;
        asl[q] = (p ^ ((r >> 1) & 3)) & 3;
        ar[q] = r;
    }

    f32x4 acc[4][4];
    #pragma unroll
    for (int i = 0; i < 4; i++)
        #pragma unroll
        for (int j = 0; j < 4; j++) acc[i][j] = (f32x4){0.f, 0.f, 0.f, 0.f};

    for (int t = 0; t < NT; t++) {
        #pragma unroll
        for (int q = 0; q < 2; q++) {             // stage A (pre-swizzled source)
            const unsigned short* src = Abf + (size_t)(m0 + ar[q]) * KP + t * 32 + asl[q] * 8;
            gload16(src, sm + (q * 256 + tid) * 16);
        }
        size_t cb = (size_t)(nb * NT + t) * 8192;
        #pragma unroll
        for (int q = 0; q < 2; q++) {             // stage B (linear chunk)
            int off = (q * 256 + tid) * 16;
            gload16(BhC + cb + off, sm + 8192 + off);
        }
        __syncthreads();                          // drains vmem+lds (compiler)
        s16x8 fah[4], fbh[4];
        #pragma unroll
        for (int f = 0; f < 4; f++) {
            fah[f] = *(const s16x8*)(sm + aoff[f]);
            fbh[f] = *(const s16x8*)(sm + 8192 + boff[f]);
        }
        #pragma unroll
        for (int i = 0; i < 4; i++)
            #pragma unroll
            for (int j = 0; j < 4; j++)
                acc[i][j] = __builtin_amdgcn_mfma_f32_16x16x32_bf16(fah[i], fbh[j], acc[i][j], 0, 0, 0);
        __syncthreads();                          // readers done before restage
    }

    if (MODE == 0) {
        float bc[4];
        #pragma unroll
        for (int f = 0; f < 4; f++) bc[f] = bias[n0 + wc * 64 + f * 16 + l15];
        float cs[4] = {0.f,0.f,0.f,0.f}, cq[4] = {0.f,0.f,0.f,0.f};
        #pragma unroll
        for (int i = 0; i < 4; i++) {
            int rowb = m0 + wr * 64 + i * 16 + l4 * 4;
            #pragma unroll
            for (int j2 = 0; j2 < 4; j2++) {
                unsigned short* hrow = Hbf + (size_t)(rowb + j2) * HD + n0 + wc * 64 + l15;
                #pragma unroll
                for (int f = 0; f < 4; f++) {
                    float v = acc[i][f][j2] + bc[f];
                    hrow[f * 16] = (unsigned short)cvtpk(v, v);   // lo16 = bf16(v)
                    cs[f] += v; cq[f] += v * v;
                }
            }
        }
        #pragma unroll
        for (int m = 16; m < 64; m <<= 1)
            #pragma unroll
            for (int f = 0; f < 4; f++) {
                cs[f] += __shfl_xor(cs[f], m, 64);
                cq[f] += __shfl_xor(cq[f], m, 64);
            }
        if (l4 == 0) {
            #pragma unroll
            for (int f = 0; f < 4; f++) {
                int col = n0 + wc * 64 + f * 16 + l15;
                sp1[(size_t)col * 1024 + mb * 2 + wr] = cs[f];
                sp2[(size_t)col * 1024 + mb * 2 + wr] = cq[f];
            }
        }
    } else {
        float bc[4], w2[4][3];
        #pragma unroll
        for (int f = 0; f < 4; f++) {
            int col = n0 + wc * 64 + f * 16 + l15;
            bc[f] = bias[col];
            w2[f][0] = Wd2[col * 3 + 0]; w2[f][1] = Wd2[col * 3 + 1]; w2[f][2] = Wd2[col * 3 + 2];
        }
        float s0[16], s1[16], s2[16];
        #pragma unroll
        for (int i = 0; i < 16; i++) { s0[i] = 0.f; s1[i] = 0.f; s2[i] = 0.f; }
        #pragma unroll
        for (int i = 0; i < 4; i++)
            #pragma unroll
            for (int j2 = 0; j2 < 4; j2++) {
                int idx = i * 4 + j2;
                #pragma unroll
                for (int f = 0; f < 4; f++) {
                    float v = frelu(acc[i][f][j2] + bc[f]);
                    s0[idx] += v * w2[f][0];
                    s1[idx] += v * w2[f][1];
                    s2[idx] += v * w2[f][2];
                }
            }
        #pragma unroll
        for (int m = 1; m < 16; m <<= 1) {
            #pragma unroll
            for (int i = 0; i < 16; i++) {
                s0[i] += __shfl_xor(s0[i], m, 64);
                s1[i] += __shfl_xor(s1[i], m, 64);
                s2[i] += __shfl_xor(s2[i], m, 64);
            }
        }
        if (l15 == 0) {
            #pragma unroll
            for (int i = 0; i < 16; i++) {
                int row = m0 + wr * 64 + (i >> 2) * 16 + l4 * 4 + (i & 3);
                atomicAdd(&domacc[(size_t)row * 3 + 0], (double)s0[i]);
                atomicAdd(&domacc[(size_t)row * 3 + 1], (double)s1[i]);
                atomicAdd(&domacc[(size_t)row * 3 + 2], (double)s2[i]);
            }
        }
    }
}

// ---- BN final: reduce 1024 fp32 partials per column in fp64 ----------------
__global__ __launch_bounds__(256)
void bnfinal(const float* __restrict__ sp1, const float* __restrict__ sp2,
             const float* __restrict__ gamma, const float* __restrict__ beta,
             float* __restrict__ scale, float* __restrict__ shift)
{
    int c = blockIdx.x, t = threadIdx.x;
    const float* p1 = sp1 + (size_t)c * 1024;
    const float* p2 = sp2 + (size_t)c * 1024;
    double S = (double)p1[t] + (double)p1[t + 256] + (double)p1[t + 512] + (double)p1[t + 768];
    double Q = (double)p2[t] + (double)p2[t + 256] + (double)p2[t + 512] + (double)p2[t + 768];
    #pragma unroll
    for (int m = 1; m < 64; m <<= 1) { S += __shfl_xor(S, m, 64); Q += __shfl_xor(Q, m, 64); }
    __shared__ double sd1[4], sd2[4];
    int w = t >> 6;
    if ((t & 63) == 0) { sd1[w] = S; sd2[w] = Q; }
    __syncthreads();
    if (t == 0) {
        double Sa = sd1[0] + sd1[1] + sd1[2] + sd1[3];
        double Qa = sd2[0] + sd2[1] + sd2[2] + sd2[3];
        double mu  = Sa * (1.0 / 65536.0);
        double var = Qa * (1.0 / 65536.0) - mu * mu;
        double inv = 1.0 / sqrt(var + 1e-5);
        double sc  = inv * (double)gamma[c];
        double sh  = (double)beta[c] - mu * sc;
        scale[c] = (float)sc;
        shift[c] = (float)sh;
    }
}

// ---- dom_out finalize pass A: write outdom, flag borderline rows -----------
__global__ __launch_bounds__(256)
void domfinal_a(const double* __restrict__ domacc, const float* __restrict__ bd2,
                float* __restrict__ outdom, int* __restrict__ fixmeta, int* __restrict__ fixlist)
{
    int r = blockIdx.x * 256 + threadIdx.x;
    double v0 = domacc[(size_t)r * 3 + 0] + (double)bd2[0];
    double v1 = domacc[(size_t)r * 3 + 1] + (double)bd2[1];
    double v2 = domacc[(size_t)r * 3 + 2] + (double)bd2[2];
    outdom[(size_t)r * 3 + 0] = (float)v0;
    outdom[(size_t)r * 3 + 1] = (float)v1;
    outdom[(size_t)r * 3 + 2] = (float)v2;
    double mx01 = v0 > v1 ? v0 : v1, mn01 = v0 > v1 ? v1 : v0;
    double best = mx01 > v2 ? mx01 : v2;
    double m2   = mx01 > v2 ? (mn01 > v2 ? mn01 : v2) : mx01;
    if (best - m2 < 1.5e-2) {
        int p = atomicAdd(fixmeta, 1);
        fixlist[p] = r;
    }
}

// ---- exact recompute of dom_out for flagged rows, FROM x (fp32) ------------
// FR=24 rows/block, thread owns 3 cols x ALL 24 rows (acc[24][3], static).
// Key insight from r10-13: wall was W-bandwidth (each chunk reads full
// W1+Wd1 = 4.65MB; FR=8 -> 3.2GB, FR=2 -> 13GB). FR=24 cuts traffic to
// ~1GB AND spreads ~225 blocks over 256 CUs (FLOP wall ~95us).
// ft held in LDS fp32 (73.7KB); xs k-tiled (24x112). ~86KB -> 1 block/CU.
#define FXR 24
__global__ __launch_bounds__(256)
void fixrow_x(const int* __restrict__ fixmeta, const int* __restrict__ fixlist,
              const float* __restrict__ x, const float* __restrict__ W1,
              const float* __restrict__ b1,
              const float* __restrict__ scale, const float* __restrict__ shift,
              const float* __restrict__ Wd1, const float* __restrict__ bd1,
              const float* __restrict__ Wd2, const float* __restrict__ bd2,
              float* __restrict__ outdom)
{
    int nfix = fixmeta[0];
    __shared__ float xs[FXR][113];       // k-tile 112 (+1 pad)
    __shared__ float ft[FXR][768];
    __shared__ float redf[4][FXR][3];
    int tid = threadIdx.x;
    int lane = tid & 63, w = tid >> 6;
    int c0 = tid * 3;                    // this thread's 3 columns

    for (int base = blockIdx.x * FXR; base < nfix; base += gridDim.x * FXR) {
        int nr = nfix - base; if (nr > FXR) nr = FXR;
        float acc[FXR][3];
        #pragma unroll
        for (int i = 0; i < FXR; i++) { acc[i][0] = 0.f; acc[i][1] = 0.f; acc[i][2] = 0.f; }

        // ---- stage 1: h = x @ W1 over 7 k-tiles of 112 ----
        for (int kt = 0; kt < 7; kt++) {
            __syncthreads();             // prev tile / prev chunk readers done
            for (int i = tid; i < FXR * 112; i += 256) {
                int rr = i / 112, cc = i - rr * 112;
                int row = fixlist[base + (rr < nr ? rr : nr - 1)];
                xs[rr][cc] = x[(size_t)row * KIN + kt * 112 + cc];
            }
            __syncthreads();
            for (int kk = 0; kk < 112; kk++) {
                int k = kt * 112 + kk;
                const float* wp = W1 + (size_t)k * HD + c0;
                float w0 = wp[0], w1 = wp[1], w2 = wp[2];
                #pragma unroll
                for (int i = 0; i < FXR; i++) {
                    float xv = xs[i][kk];
                    acc[i][0] += xv * w0; acc[i][1] += xv * w1; acc[i][2] += xv * w2;
                }
            }
        }
        __syncthreads();
        // ---- BN + relu -> ft ----
        {
            float sc0 = scale[c0], sc1 = scale[c0 + 1], sc2 = scale[c0 + 2];
            float sh0 = shift[c0], sh1 = shift[c0 + 1], sh2 = shift[c0 + 2];
            float b0 = b1[c0], b1v = b1[c0 + 1], b2 = b1[c0 + 2];
            #pragma unroll
            for (int i = 0; i < FXR; i++) {
                ft[i][c0]     = frelu((acc[i][0] + b0)  * sc0 + sh0);
                ft[i][c0 + 1] = frelu((acc[i][1] + b1v) * sc1 + sh1);
                ft[i][c0 + 2] = frelu((acc[i][2] + b2)  * sc2 + sh2);
            }
        }
        __syncthreads();
        // ---- stage 2: h2 = ft @ Wd1 (ft from LDS) ----
        #pragma unroll
        for (int i = 0; i < FXR; i++) { acc[i][0] = 0.f; acc[i][1] = 0.f; acc[i][2] = 0.f; }
        for (int k = 0; k < HD; k++) {
            const float* wp = Wd1 + (size_t)k * HD + c0;
            float w0 = wp[0], w1 = wp[1], w2 = wp[2];
            #pragma unroll
            for (int i = 0; i < FXR; i++) {
                float fv = ft[i][k];
                acc[i][0] += fv * w0; acc[i][1] += fv * w1; acc[i][2] += fv * w2;
            }
        }
        // ---- project to 3 dom logits, reduce over cols ----
        {
            float bc0 = bd1[c0], bc1 = bd1[c0 + 1], bc2 = bd1[c0 + 2];
            float w2a[3][3];
            #pragma unroll
            for (int j = 0; j < 3; j++)
                #pragma unroll
                for (int d = 0; d < 3; d++) w2a[j][d] = Wd2[(c0 + j) * 3 + d];
            float y[FXR][3];
            #pragma unroll
            for (int i = 0; i < FXR; i++) {
                float h0 = frelu(acc[i][0] + bc0);
                float h1 = frelu(acc[i][1] + bc1);
                float h2 = frelu(acc[i][2] + bc2);
                y[i][0] = h0 * w2a[0][0] + h1 * w2a[1][0] + h2 * w2a[2][0];
                y[i][1] = h0 * w2a[0][1] + h1 * w2a[1][1] + h2 * w2a[2][1];
                y[i][2] = h0 * w2a[0][2] + h1 * w2a[1][2] + h2 * w2a[2][2];
            }
            #pragma unroll
            for (int m = 1; m < 64; m <<= 1)
                #pragma unroll
                for (int i = 0; i < FXR; i++) {
                    y[i][0] += __shfl_xor(y[i][0], m, 64);
                    y[i][1] += __shfl_xor(y[i][1], m, 64);
                    y[i][2] += __shfl_xor(y[i][2], m, 64);
                }
            if (lane == 0)
                #pragma unroll
                for (int i = 0; i < FXR; i++) {
                    redf[w][i][0] = y[i][0]; redf[w][i][1] = y[i][1]; redf[w][i][2] = y[i][2];
                }
        }
        __syncthreads();
        if (tid < FXR * 3) {
            int r = tid / 3, d = tid - r * 3;
            if (r < nr) {
                int row = fixlist[base + r];
                double v = (double)redf[0][r][d] + redf[1][r][d] + redf[2][r][d]
                         + redf[3][r][d] + (double)bd2[d];
                outdom[(size_t)row * 3 + d] = (float)v;
            }
        }
    }
}

// ---- pass B: argmax + bucket (block-aggregated atomics) --------------------
__global__ __launch_bounds__(256)
void domfinal_b(const float* __restrict__ outdom, int* __restrict__ cnt, int* __restrict__ lists)
{
    __shared__ int lcnt[3], base[3];
    int tid = threadIdx.x;
    if (tid < 3) lcnt[tid] = 0;
    __syncthreads();
    int r = blockIdx.x * 256 + tid;
    float v0 = outdom[(size_t)r * 3 + 0];
    float v1 = outdom[(size_t)r * 3 + 1];
    float v2 = outdom[(size_t)r * 3 + 2];
    int p = 0; float best = v0;
    if (v1 > best) { best = v1; p = 1; }
    if (v2 > best) { best = v2; p = 2; }
    int lpos = atomicAdd(&lcnt[p], 1);
    __syncthreads();
    if (tid < 3) base[tid] = atomicAdd(&cnt[tid], lcnt[tid]);
    __syncthreads();
    lists[(size_t)p * BATCH + base[p] + lpos] = r;
}

// ---- expert MLP: 32 same-domain rows/block; feat read as bf16 --------------
__global__ __launch_bounds__(256)
void expert_kernel(const unsigned short* __restrict__ fbf,
                   const int* __restrict__ cnt, const int* __restrict__ lists,
                   const float* __restrict__ Wa, const float* __restrict__ ba,
                   const float* __restrict__ Wb, const float* __restrict__ bb,
                   float* __restrict__ outs)
{
    int d = blockIdx.y;
    int start = blockIdx.x * 32;
    int count = cnt[d];
    if (start >= count) return;
    int nrows = count - start; if (nrows > 32) nrows = 32;

    __shared__ int   rowidx[32];
    __shared__ float fs[32][68];
    __shared__ float wsa[64][64];
    __shared__ float hid[32][64];

    int tid = threadIdx.x;
    if (tid < 32) {
        int i = tid < nrows ? tid : (nrows - 1);
        rowidx[tid] = lists[(size_t)d * BATCH + start + i];
    }
    __syncthreads();

    int rr = tid >> 3;
    int g  = tid & 7;
    int fcol = g << 3;

    float hacc[8] = {0, 0, 0, 0, 0, 0, 0, 0};

    for (int k0 = 0; k0 < HD; k0 += 64) {
        {
            int row = rowidx[rr];
            s16x8 hv = *(const s16x8*)(fbf + (size_t)row * HD + k0 + fcol);
            #pragma unroll
            for (int e = 0; e < 8; e++)
                fs[rr][fcol + e] = bf2f((unsigned short)hv[e]);
        }
        #pragma unroll
        for (int rep = 0; rep < 4; rep++) {
            int idx = rep * 256 + tid;
            int kk = idx >> 4;
            int f4 = (idx & 15) << 2;
            *(float4*)&wsa[kk][f4] = *(const float4*)(Wa + ((size_t)d * HD + k0 + kk) * 64 + f4);
        }
        __syncthreads();
        #pragma unroll 8
        for (int kk = 0; kk < 64; kk++) {
            float fv = fs[rr][kk];
            const float* wrow = &wsa[kk][g << 3];
            float4 w0 = *(const float4*)wrow;
            float4 w1 = *(const float4*)(wrow + 4);
            hacc[0] += fv * w0.x; hacc[1] += fv * w0.y; hacc[2] += fv * w0.z; hacc[3] += fv * w0.w;
            hacc[4] += fv * w1.x; hacc[5] += fv * w1.y; hacc[6] += fv * w1.z; hacc[7] += fv * w1.w;
        }
        __syncthreads();
    }

    #pragma unroll
    for (int j = 0; j < 8; j++) {
        float v = hacc[j] + ba[d * 64 + fcol + j];
        hid[rr][fcol + j] = frelu(v);
    }
    __syncthreads();

    for (int o = tid; o < 320; o += 256) {
        int r2 = o / 10, c = o - r2 * 10;
        if (r2 < nrows) {
            float s = 0.f;
            #pragma unroll 16
            for (int l = 0; l < 64; l++) s += hid[r2][l] * Wb[((size_t)d * 64 + l) * 10 + c];
            outs[(size_t)rowidx[r2] * 10 + c] = s + bb[d * 10 + c];
        }
    }
}

// ---------------------------------------------------------------------------
extern "C" void kernel_launch(void* const* d_in, const int* in_sizes, int n_in,
                              void* d_out, int out_size, void* d_ws, size_t ws_size,
                              hipStream_t stream)
{
    const float* x     = (const float*)d_in[0];
    const float* W1    = (const float*)d_in[1];
    const float* b1    = (const float*)d_in[2];
    const float* gamma = (const float*)d_in[3];
    const float* beta  = (const float*)d_in[4];
    const float* Wd1   = (const float*)d_in[5];
    const float* bd1   = (const float*)d_in[6];
    const float* Wd2   = (const float*)d_in[7];
    const float* bd2   = (const float*)d_in[8];
    const float* Wa    = (const float*)d_in[9];
    const float* ba    = (const float*)d_in[10];
    const float* Wb    = (const float*)d_in[11];
    const float* bb    = (const float*)d_in[12];

    float* out    = (float*)d_out;
    float* outs   = out;
    float* outdom = out + (size_t)BATCH * 10;

    const int NT1 = 25, NT2 = 24;

    char* ws = (char*)d_ws;
    size_t off = 0;
    unsigned short* hbf = (unsigned short*)(ws + off); off += (size_t)BATCH * HD * 2;
    unsigned short* xbf = (unsigned short*)(ws + off); off += (size_t)BATCH * 800 * 2;
    unsigned short* fbf = xbf;   // alias: xbf dead after GEMM1; 768 <= 800 per row
    char*  W1hC   = ws + off;            off += (size_t)6 * NT1 * 8192;
    char*  Wd1hC  = ws + off;            off += (size_t)6 * NT2 * 8192;
    float* sp1    = (float*)(ws + off);  off += (size_t)HD * 1024 * 4;
    float* sp2    = (float*)(ws + off);  off += (size_t)HD * 1024 * 4;
    float* scale  = (float*)(ws + off);  off += HD * 4;
    float* shift  = (float*)(ws + off);  off += HD * 4;
    size_t zoff = off;
    double* domacc = (double*)(ws + off); off += (size_t)BATCH * 3 * 8;
    int*    cnt    = (int*)(ws + off);    off += 64;
    int*    fixmeta= (int*)(ws + off);    off += 64;
    size_t zbytes = off - zoff;
    int*    lists  = (int*)(ws + off);    off += (size_t)3 * BATCH * 4;
    int*    fixlist= (int*)(ws + off);    off += (size_t)BATCH * 4;

    hipMemsetAsync(ws + zoff, 0, zbytes, stream);

    tileW<<<6 * NT1, 256, 0, stream>>>(W1, W1hC, KIN, HD, NT1);
    tileW<<<6 * NT2, 256, 0, stream>>>(Wd1, Wd1hC, HD, HD, NT2);
    cvtX<<<BATCH * 100 / 256, 256, 0, stream>>>(x, xbf);

    gemm97<0><<<3072, 256, 0, stream>>>(xbf, W1hC, b1, hbf,
                                        nullptr, nullptr, sp1, sp2, 800, NT1);
    bnfinal<<<HD, 256, 0, stream>>>(sp1, sp2, gamma, beta, scale, shift);
    featBN<<<BATCH * 96 / 256, 256, 0, stream>>>(hbf, scale, shift, fbf);
    gemm97<1><<<3072, 256, 0, stream>>>(fbf, Wd1hC, bd1, nullptr,
                                        Wd2, domacc, nullptr, nullptr, HD, NT2);
    domfinal_a<<<BATCH / 256, 256, 0, stream>>>(domacc, bd2, outdom, fixmeta, fixlist);
    fixrow_x<<<2048, 256, 0, stream>>>(fixmeta, fixlist, x, W1, b1, scale, shift,
                                       Wd1, bd1, Wd2, bd2, outdom);
    domfinal_b<<<BATCH / 256, 256, 0, stream>>>(outdom, cnt, lists);
    dim3 eg(BATCH / 32, 3);
    expert_kernel<<<eg, 256, 0, stream>>>(fbf, cnt, lists, Wa, ba, Wb, bb, outs);
}

// Round 15
// 1002.280 us; speedup vs baseline: 1.3207x; 1.3207x over previous
//
#include <hip/hip_runtime.h>
#include <math.h>

#define BATCH 65536
#define KIN   784
#define HD    768

typedef float f32x4 __attribute__((ext_vector_type(4)));
typedef short s16x8 __attribute__((ext_vector_type(8)));
typedef unsigned int __attribute__((address_space(3))) lds_u32;
typedef const unsigned int __attribute__((address_space(1))) glb_u32;

__device__ __forceinline__ float frelu(float x){ return x > 0.f ? x : 0.f; }

// packed bf16 convert: dst = {lo16=cvt(a), hi16=cvt(b)}
__device__ __forceinline__ unsigned int cvtpk(float a, float b){
    unsigned int r;
    asm("v_cvt_pk_bf16_f32 %0, %1, %2" : "=v"(r) : "v"(a), "v"(b));
    return r;
}
__device__ __forceinline__ unsigned short f2bf(float v){
    unsigned int u = __builtin_bit_cast(unsigned int, v);
    u += 0x7FFFu + ((u >> 16) & 1u);
    return (unsigned short)(u >> 16);
}
__device__ __forceinline__ float bf2f(unsigned short s){
    unsigned int u = ((unsigned int)s) << 16;
    return __builtin_bit_cast(float, u);
}
__device__ __forceinline__ void gload16(const void* g, void* l){
    __builtin_amdgcn_global_load_lds((glb_u32*)g, (lds_u32*)l, 16, 0, 0);
}

// ---------------------------------------------------------------------------
// x [B,784] fp32 -> xbf [B,800] bf16 (pad zeroed). One uint4 (8 elems)/thread.
// ---------------------------------------------------------------------------
__global__ __launch_bounds__(256)
void cvtX(const float* __restrict__ x, unsigned short* __restrict__ xbf)
{
    int idx = blockIdx.x * 256 + threadIdx.x;     // BATCH*100 total
    int row = idx / 100, c = (idx - row * 100) * 8;
    uint4 o = make_uint4(0, 0, 0, 0);
    if (c < KIN) {
        const float* p = x + (size_t)row * KIN + c;
        float4 a = *(const float4*)p;
        float4 b = *(const float4*)(p + 4);
        o.x = cvtpk(a.x, a.y); o.y = cvtpk(a.z, a.w);
        o.z = cvtpk(b.x, b.y); o.w = cvtpk(b.z, b.w);
    }
    *(uint4*)(xbf + (size_t)row * 800 + c) = o;
}

// ---------------------------------------------------------------------------
// feat = relu(hbf*scale + shift) -> fbf (bf16). 8 elems/thread.
// ---------------------------------------------------------------------------
__global__ __launch_bounds__(256)
void featBN(const unsigned short* __restrict__ hbf,
            const float* __restrict__ scale, const float* __restrict__ shift,
            unsigned short* __restrict__ fbf)
{
    int idx = blockIdx.x * 256 + threadIdx.x;     // BATCH*96 total
    int row = idx / 96, c = (idx - row * 96) * 8;
    s16x8 hv = *(const s16x8*)(hbf + (size_t)row * HD + c);
    float4 s0 = *(const float4*)(scale + c), s1 = *(const float4*)(scale + c + 4);
    float4 t0 = *(const float4*)(shift + c), t1 = *(const float4*)(shift + c + 4);
    float v[8];
    v[0] = frelu(bf2f((unsigned short)hv[0]) * s0.x + t0.x);
    v[1] = frelu(bf2f((unsigned short)hv[1]) * s0.y + t0.y);
    v[2] = frelu(bf2f((unsigned short)hv[2]) * s0.z + t0.z);
    v[3] = frelu(bf2f((unsigned short)hv[3]) * s0.w + t0.w);
    v[4] = frelu(bf2f((unsigned short)hv[4]) * s1.x + t1.x);
    v[5] = frelu(bf2f((unsigned short)hv[5]) * s1.y + t1.y);
    v[6] = frelu(bf2f((unsigned short)hv[6]) * s1.z + t1.z);
    v[7] = frelu(bf2f((unsigned short)hv[7]) * s1.w + t1.w);
    uint4 o;
    o.x = cvtpk(v[0], v[1]); o.y = cvtpk(v[2], v[3]);
    o.z = cvtpk(v[4], v[5]); o.w = cvtpk(v[6], v[7]);
    *(uint4*)(fbf + (size_t)row * HD + c) = o;
}

// ---------------------------------------------------------------------------
// Pre-tile W[K][N] fp32 -> bf16 per-(nb,t) 8KB chunks = exact swizzled LDS
// image: byte (r*64+p*16+e*2) = bf16 of W[t*32+s*8+e][nb*128+r], s=p^((r>>1)&3)
// ---------------------------------------------------------------------------
__global__ __launch_bounds__(256)
void tileW(const float* __restrict__ W, char* __restrict__ Wh, int K, int N, int NT)
{
    int chunk = blockIdx.x;
    int nb = chunk / NT, t = chunk - nb * NT;
    int tid = threadIdx.x;
    #pragma unroll
    for (int q = 0; q < 2; q++) {
        int idx = q * 256 + tid;
        int r = idx >> 2, p = idx & 3;
        int s = (p ^ ((r >> 1) & 3)) & 3;
        int kb = t * 32 + s * 8;
        int n = nb * 128 + r;
        s16x8 hv;
        #pragma unroll
        for (int e = 0; e < 8; e++) {
            int k = kb + e;
            float v = (k < K) ? W[(size_t)k * N + n] : 0.f;
            hv[e] = (short)f2bf(v);
        }
        *(s16x8*)(Wh + (size_t)chunk * 8192 + idx * 16) = hv;
    }
}

// ---------------------------------------------------------------------------
// m97-shaped bf16 GEMM: BOTH operands staged via global_load_lds (A from a
// bf16 row-major array with per-lane pre-swizzled k-offsets; B from pre-tiled
// chunks). ZERO VALU in the K-loop. Single 16KB buffer, 2-barrier loop.
// MODE 0: A=xbf(KP=800); epilogue h(bf16) + fused BN column partials.
// MODE 1: A=fbf(KP=768); epilogue a=relu(acc+bd1); domacc += a @ Wd2.
// ---------------------------------------------------------------------------
template<int MODE>
__global__ __launch_bounds__(256, 3)
void gemm97(const unsigned short* __restrict__ Abf,
            const char* __restrict__ BhC,
            const float* __restrict__ bias,
            unsigned short* __restrict__ Hbf,
            const float* __restrict__ Wd2, double* __restrict__ domacc,
            float* __restrict__ sp1, float* __restrict__ sp2,
            int KP, int NT)
{
    __shared__ __align__(16) char sm[16384];      // A 8KB | B 8KB

    int bid = blockIdx.x;
    int wg = (bid & 7) * 384 + (bid >> 3);        // XCD-contiguous remap
    int mb = wg / 6, nb = wg - mb * 6;
    int m0 = mb << 7, n0 = nb << 7;

    int tid = threadIdx.x;
    int lane = tid & 63, wid = tid >> 6;
    int wr = wid >> 1, wc = wid & 1;
    int l15 = lane & 15, l4 = lane >> 4;

    int aoff[4], boff[4];
    #pragma unroll
    for (int f = 0; f < 4; f++) {
        int ra = wr * 64 + f * 16 + l15;
        aoff[f] = ra * 64 + (((l4 ^ (ra >> 1)) & 3) << 4);
        int rb = wc * 64 + f * 16 + l15;
        boff[f] = rb * 64 + (((l4 ^ (rb >> 1)) & 3) << 4);
    }

    // staging: idx = q*256+tid -> row r, phys slot p; source k-group s
    int ar[2], asl[2];
    #pragma unroll
    for (int q = 0; q < 2; q++) {
        int idx = q * 256 + tid;
        int r = idx >> 2, p = idx & 3;
        asl[q] = (p ^ ((r >> 1) & 3)) & 3;
        ar[q] = r;
    }

    f32x4 acc[4][4];
    #pragma unroll
    for (int i = 0; i < 4; i++)
        #pragma unroll
        for (int j = 0; j < 4; j++) acc[i][j] = (f32x4){0.f, 0.f, 0.f, 0.f};

    for (int t = 0; t < NT; t++) {
        #pragma unroll
        for (int q = 0; q < 2; q++) {             // stage A (pre-swizzled source)
            const unsigned short* src = Abf + (size_t)(m0 + ar[q]) * KP + t * 32 + asl[q] * 8;
            gload16(src, sm + (q * 256 + tid) * 16);
        }
        size_t cb = (size_t)(nb * NT + t) * 8192;
        #pragma unroll
        for (int q = 0; q < 2; q++) {             // stage B (linear chunk)
            int off = (q * 256 + tid) * 16;
            gload16(BhC + cb + off, sm + 8192 + off);
        }
        __syncthreads();                          // drains vmem+lds (compiler)
        s16x8 fah[4], fbh[4];
        #pragma unroll
        for (int f = 0; f < 4; f++) {
            fah[f] = *(const s16x8*)(sm + aoff[f]);
            fbh[f] = *(const s16x8*)(sm + 8192 + boff[f]);
        }
        #pragma unroll
        for (int i = 0; i < 4; i++)
            #pragma unroll
            for (int j = 0; j < 4; j++)
                acc[i][j] = __builtin_amdgcn_mfma_f32_16x16x32_bf16(fah[i], fbh[j], acc[i][j], 0, 0, 0);
        __syncthreads();                          // readers done before restage
    }

    if (MODE == 0) {
        float bc[4];
        #pragma unroll
        for (int f = 0; f < 4; f++) bc[f] = bias[n0 + wc * 64 + f * 16 + l15];
        float cs[4] = {0.f,0.f,0.f,0.f}, cq[4] = {0.f,0.f,0.f,0.f};
        #pragma unroll
        for (int i = 0; i < 4; i++) {
            int rowb = m0 + wr * 64 + i * 16 + l4 * 4;
            #pragma unroll
            for (int j2 = 0; j2 < 4; j2++) {
                unsigned short* hrow = Hbf + (size_t)(rowb + j2) * HD + n0 + wc * 64 + l15;
                #pragma unroll
                for (int f = 0; f < 4; f++) {
                    float v = acc[i][f][j2] + bc[f];
                    hrow[f * 16] = (unsigned short)cvtpk(v, v);   // lo16 = bf16(v)
                    cs[f] += v; cq[f] += v * v;
                }
            }
        }
        #pragma unroll
        for (int m = 16; m < 64; m <<= 1)
            #pragma unroll
            for (int f = 0; f < 4; f++) {
                cs[f] += __shfl_xor(cs[f], m, 64);
                cq[f] += __shfl_xor(cq[f], m, 64);
            }
        if (l4 == 0) {
            #pragma unroll
            for (int f = 0; f < 4; f++) {
                int col = n0 + wc * 64 + f * 16 + l15;
                sp1[(size_t)col * 1024 + mb * 2 + wr] = cs[f];
                sp2[(size_t)col * 1024 + mb * 2 + wr] = cq[f];
            }
        }
    } else {
        float bc[4], w2[4][3];
        #pragma unroll
        for (int f = 0; f < 4; f++) {
            int col = n0 + wc * 64 + f * 16 + l15;
            bc[f] = bias[col];
            w2[f][0] = Wd2[col * 3 + 0]; w2[f][1] = Wd2[col * 3 + 1]; w2[f][2] = Wd2[col * 3 + 2];
        }
        float s0[16], s1[16], s2[16];
        #pragma unroll
        for (int i = 0; i < 16; i++) { s0[i] = 0.f; s1[i] = 0.f; s2[i] = 0.f; }
        #pragma unroll
        for (int i = 0; i < 4; i++)
            #pragma unroll
            for (int j2 = 0; j2 < 4; j2++) {
                int idx = i * 4 + j2;
                #pragma unroll
                for (int f = 0; f < 4; f++) {
                    float v = frelu(acc[i][f][j2] + bc[f]);
                    s0[idx] += v * w2[f][0];
                    s1[idx] += v * w2[f][1];
                    s2[idx] += v * w2[f][2];
                }
            }
        #pragma unroll
        for (int m = 1; m < 16; m <<= 1) {
            #pragma unroll
            for (int i = 0; i < 16; i++) {
                s0[i] += __shfl_xor(s0[i], m, 64);
                s1[i] += __shfl_xor(s1[i], m, 64);
                s2[i] += __shfl_xor(s2[i], m, 64);
            }
        }
        if (l15 == 0) {
            #pragma unroll
            for (int i = 0; i < 16; i++) {
                int row = m0 + wr * 64 + (i >> 2) * 16 + l4 * 4 + (i & 3);
                atomicAdd(&domacc[(size_t)row * 3 + 0], (double)s0[i]);
                atomicAdd(&domacc[(size_t)row * 3 + 1], (double)s1[i]);
                atomicAdd(&domacc[(size_t)row * 3 + 2], (double)s2[i]);
            }
        }
    }
}

// ---- BN final: reduce 1024 fp32 partials per column in fp64 ----------------
__global__ __launch_bounds__(256)
void bnfinal(const float* __restrict__ sp1, const float* __restrict__ sp2,
             const float* __restrict__ gamma, const float* __restrict__ beta,
             float* __restrict__ scale, float* __restrict__ shift)
{
    int c = blockIdx.x, t = threadIdx.x;
    const float* p1 = sp1 + (size_t)c * 1024;
    const float* p2 = sp2 + (size_t)c * 1024;
    double S = (double)p1[t] + (double)p1[t + 256] + (double)p1[t + 512] + (double)p1[t + 768];
    double Q = (double)p2[t] + (double)p2[t + 256] + (double)p2[t + 512] + (double)p2[t + 768];
    #pragma unroll
    for (int m = 1; m < 64; m <<= 1) { S += __shfl_xor(S, m, 64); Q += __shfl_xor(Q, m, 64); }
    __shared__ double sd1[4], sd2[4];
    int w = t >> 6;
    if ((t & 63) == 0) { sd1[w] = S; sd2[w] = Q; }
    __syncthreads();
    if (t == 0) {
        double Sa = sd1[0] + sd1[1] + sd1[2] + sd1[3];
        double Qa = sd2[0] + sd2[1] + sd2[2] + sd2[3];
        double mu  = Sa * (1.0 / 65536.0);
        double var = Qa * (1.0 / 65536.0) - mu * mu;
        double inv = 1.0 / sqrt(var + 1e-5);
        double sc  = inv * (double)gamma[c];
        double sh  = (double)beta[c] - mu * sc;
        scale[c] = (float)sc;
        shift[c] = (float)sh;
    }
}

// ---- dom_out finalize pass A: write outdom, flag borderline rows -----------
__global__ __launch_bounds__(256)
void domfinal_a(const double* __restrict__ domacc, const float* __restrict__ bd2,
                float* __restrict__ outdom, int* __restrict__ fixmeta, int* __restrict__ fixlist)
{
    int r = blockIdx.x * 256 + threadIdx.x;
    double v0 = domacc[(size_t)r * 3 + 0] + (double)bd2[0];
    double v1 = domacc[(size_t)r * 3 + 1] + (double)bd2[1];
    double v2 = domacc[(size_t)r * 3 + 2] + (double)bd2[2];
    outdom[(size_t)r * 3 + 0] = (float)v0;
    outdom[(size_t)r * 3 + 1] = (float)v1;
    outdom[(size_t)r * 3 + 2] = (float)v2;
    double mx01 = v0 > v1 ? v0 : v1, mn01 = v0 > v1 ? v1 : v0;
    double best = mx01 > v2 ? mx01 : v2;
    double m2   = mx01 > v2 ? (mn01 > v2 ? mn01 : v2) : mx01;
    if (best - m2 < 1.5e-2) {
        int p = atomicAdd(fixmeta, 1);
        fixlist[p] = r;
    }
}

// ---- exact recompute of dom_out for flagged rows, FROM x (fp32) ------------
// v4: thread = (col-group of 6, k-half). Chain 392+384 (1/4 of v1's 1552).
// 16 rows/block give 96 independent FMAs/iter (ILP latency hiding) + W reuse;
// ft fp32 in LDS (48KB -> 3 blocks/CU resident). Halves combine through LDS
// in fixed order; stage-2 partials reuse ft; Wd2 projection shuffle-reduced.
// r10-14 lesson: wall = chain x latency / waves-per-SIMD; this shortens chain
// 4x AND keeps 12 waves/CU AND 16-row W reuse.
#define FXR 16
__global__ __launch_bounds__(256)
void fixrow_x(const int* __restrict__ fixmeta, const int* __restrict__ fixlist,
              const float* __restrict__ x, const float* __restrict__ W1,
              const float* __restrict__ b1,
              const float* __restrict__ scale, const float* __restrict__ shift,
              const float* __restrict__ Wd1, const float* __restrict__ bd1,
              const float* __restrict__ Wd2, const float* __restrict__ bd2,
              float* __restrict__ outdom)
{
    int nfix = fixmeta[0];
    __shared__ float ft[FXR][768];
    __shared__ int rowidx[FXR];
    __shared__ float yred[2][FXR][3];
    int tid = threadIdx.x;
    int g = tid & 127, half = tid >> 7;
    int c0 = g * 6;
    int lane = tid & 63;

    for (int base = blockIdx.x * FXR; base < nfix; base += gridDim.x * FXR) {
        int nr = nfix - base; if (nr > FXR) nr = FXR;
        __syncthreads();                       // previous-iteration readers done
        if (tid < FXR) rowidx[tid] = fixlist[base + (tid < nr ? tid : nr - 1)];
        __syncthreads();
        int rw[FXR];
        #pragma unroll
        for (int i = 0; i < FXR; i++) rw[i] = rowidx[i];

        float acc[FXR][6];
        #pragma unroll
        for (int i = 0; i < FXR; i++)
            #pragma unroll
            for (int j = 0; j < 6; j++) acc[i][j] = 0.f;

        // ---- stage 1 partial: h_half = x[:, khalf] @ W1[khalf, c0..c0+5] ----
        {
            int k0 = half * 392;
            for (int k = k0; k < k0 + 392; k++) {
                const float2* wp = (const float2*)(W1 + (size_t)k * HD + c0);
                float2 wa = wp[0], wb = wp[1], wcv = wp[2];
                #pragma unroll
                for (int i = 0; i < FXR; i++) {
                    float xv = x[(size_t)rw[i] * KIN + k];   // lane-broadcast load
                    acc[i][0] += xv * wa.x;  acc[i][1] += xv * wa.y;
                    acc[i][2] += xv * wb.x;  acc[i][3] += xv * wb.y;
                    acc[i][4] += xv * wcv.x; acc[i][5] += xv * wcv.y;
                }
            }
        }
        __syncthreads();
        if (half == 0) {
            #pragma unroll
            for (int i = 0; i < FXR; i++) {
                ft[i][c0+0] = acc[i][0]; ft[i][c0+1] = acc[i][1]; ft[i][c0+2] = acc[i][2];
                ft[i][c0+3] = acc[i][3]; ft[i][c0+4] = acc[i][4]; ft[i][c0+5] = acc[i][5];
            }
        }
        __syncthreads();
        if (half == 1) {
            float bb[6], sc[6], sh[6];
            #pragma unroll
            for (int j = 0; j < 6; j++) { bb[j] = b1[c0+j]; sc[j] = scale[c0+j]; sh[j] = shift[c0+j]; }
            #pragma unroll
            for (int i = 0; i < FXR; i++)
                #pragma unroll
                for (int j = 0; j < 6; j++) {
                    float s = ft[i][c0+j] + acc[i][j];
                    ft[i][c0+j] = frelu((s + bb[j]) * sc[j] + sh[j]);
                }
        }
        __syncthreads();

        // ---- stage 2 partial: ft @ Wd1[khalf, c0..c0+5] ----
        #pragma unroll
        for (int i = 0; i < FXR; i++)
            #pragma unroll
            for (int j = 0; j < 6; j++) acc[i][j] = 0.f;
        {
            int k0 = half * 384;
            for (int k = k0; k < k0 + 384; k++) {
                const float2* wp = (const float2*)(Wd1 + (size_t)k * HD + c0);
                float2 wa = wp[0], wb = wp[1], wcv = wp[2];
                #pragma unroll
                for (int i = 0; i < FXR; i++) {
                    float fv = ft[i][k];                     // LDS broadcast
                    acc[i][0] += fv * wa.x;  acc[i][1] += fv * wa.y;
                    acc[i][2] += fv * wb.x;  acc[i][3] += fv * wb.y;
                    acc[i][4] += fv * wcv.x; acc[i][5] += fv * wcv.y;
                }
            }
        }
        __syncthreads();                       // everyone done reading ft
        if (half == 0) {
            #pragma unroll
            for (int i = 0; i < FXR; i++) {
                ft[i][c0+0] = acc[i][0]; ft[i][c0+1] = acc[i][1]; ft[i][c0+2] = acc[i][2];
                ft[i][c0+3] = acc[i][3]; ft[i][c0+4] = acc[i][4]; ft[i][c0+5] = acc[i][5];
            }
        }
        __syncthreads();
        if (half == 1) {
            float bd[6], w20[6], w21[6], w22[6];
            #pragma unroll
            for (int j = 0; j < 6; j++) {
                bd[j]  = bd1[c0+j];
                w20[j] = Wd2[(c0+j) * 3 + 0];
                w21[j] = Wd2[(c0+j) * 3 + 1];
                w22[j] = Wd2[(c0+j) * 3 + 2];
            }
            float y[FXR][3];
            #pragma unroll
            for (int i = 0; i < FXR; i++) { y[i][0] = 0.f; y[i][1] = 0.f; y[i][2] = 0.f; }
            #pragma unroll
            for (int i = 0; i < FXR; i++)
                #pragma unroll
                for (int j = 0; j < 6; j++) {
                    float h2 = frelu(ft[i][c0+j] + acc[i][j] + bd[j]);
                    y[i][0] += h2 * w20[j]; y[i][1] += h2 * w21[j]; y[i][2] += h2 * w22[j];
                }
            #pragma unroll
            for (int m = 1; m < 64; m <<= 1)
                #pragma unroll
                for (int i = 0; i < FXR; i++) {
                    y[i][0] += __shfl_xor(y[i][0], m, 64);
                    y[i][1] += __shfl_xor(y[i][1], m, 64);
                    y[i][2] += __shfl_xor(y[i][2], m, 64);
                }
            int wsel = (tid >> 6) & 1;         // wave2 -> 0, wave3 -> 1
            if (lane == 0)
                #pragma unroll
                for (int i = 0; i < FXR; i++) {
                    yred[wsel][i][0] = y[i][0];
                    yred[wsel][i][1] = y[i][1];
                    yred[wsel][i][2] = y[i][2];
                }
        }
        __syncthreads();
        if (tid < FXR * 3) {
            int r = tid / 3, d = tid - r * 3;
            if (r < nr) {
                int row = rowidx[r];
                double v = (double)yred[0][r][d] + (double)yred[1][r][d] + (double)bd2[d];
                outdom[(size_t)row * 3 + d] = (float)v;
            }
        }
    }
}

// ---- pass B: argmax + bucket (block-aggregated atomics) --------------------
__global__ __launch_bounds__(256)
void domfinal_b(const float* __restrict__ outdom, int* __restrict__ cnt, int* __restrict__ lists)
{
    __shared__ int lcnt[3], base[3];
    int tid = threadIdx.x;
    if (tid < 3) lcnt[tid] = 0;
    __syncthreads();
    int r = blockIdx.x * 256 + tid;
    float v0 = outdom[(size_t)r * 3 + 0];
    float v1 = outdom[(size_t)r * 3 + 1];
    float v2 = outdom[(size_t)r * 3 + 2];
    int p = 0; float best = v0;
    if (v1 > best) { best = v1; p = 1; }
    if (v2 > best) { best = v2; p = 2; }
    int lpos = atomicAdd(&lcnt[p], 1);
    __syncthreads();
    if (tid < 3) base[tid] = atomicAdd(&cnt[tid], lcnt[tid]);
    __syncthreads();
    lists[(size_t)p * BATCH + base[p] + lpos] = r;
}

// ---- expert MLP: 32 same-domain rows/block; feat read as bf16 --------------
__global__ __launch_bounds__(256)
void expert_kernel(const unsigned short* __restrict__ fbf,
                   const int* __restrict__ cnt, const int* __restrict__ lists,
                   const float* __restrict__ Wa, const float* __restrict__ ba,
                   const float* __restrict__ Wb, const float* __restrict__ bb,
                   float* __restrict__ outs)
{
    int d = blockIdx.y;
    int start = blockIdx.x * 32;
    int count = cnt[d];
    if (start >= count) return;
    int nrows = count - start; if (nrows > 32) nrows = 32;

    __shared__ int   rowidx[32];
    __shared__ float fs[32][68];
    __shared__ float wsa[64][64];
    __shared__ float hid[32][64];

    int tid = threadIdx.x;
    if (tid < 32) {
        int i = tid < nrows ? tid : (nrows - 1);
        rowidx[tid] = lists[(size_t)d * BATCH + start + i];
    }
    __syncthreads();

    int rr = tid >> 3;
    int g  = tid & 7;
    int fcol = g << 3;

    float hacc[8] = {0, 0, 0, 0, 0, 0, 0, 0};

    for (int k0 = 0; k0 < HD; k0 += 64) {
        {
            int row = rowidx[rr];
            s16x8 hv = *(const s16x8*)(fbf + (size_t)row * HD + k0 + fcol);
            #pragma unroll
            for (int e = 0; e < 8; e++)
                fs[rr][fcol + e] = bf2f((unsigned short)hv[e]);
        }
        #pragma unroll
        for (int rep = 0; rep < 4; rep++) {
            int idx = rep * 256 + tid;
            int kk = idx >> 4;
            int f4 = (idx & 15) << 2;
            *(float4*)&wsa[kk][f4] = *(const float4*)(Wa + ((size_t)d * HD + k0 + kk) * 64 + f4);
        }
        __syncthreads();
        #pragma unroll 8
        for (int kk = 0; kk < 64; kk++) {
            float fv = fs[rr][kk];
            const float* wrow = &wsa[kk][g << 3];
            float4 w0 = *(const float4*)wrow;
            float4 w1 = *(const float4*)(wrow + 4);
            hacc[0] += fv * w0.x; hacc[1] += fv * w0.y; hacc[2] += fv * w0.z; hacc[3] += fv * w0.w;
            hacc[4] += fv * w1.x; hacc[5] += fv * w1.y; hacc[6] += fv * w1.z; hacc[7] += fv * w1.w;
        }
        __syncthreads();
    }

    #pragma unroll
    for (int j = 0; j < 8; j++) {
        float v = hacc[j] + ba[d * 64 + fcol + j];
        hid[rr][fcol + j] = frelu(v);
    }
    __syncthreads();

    for (int o = tid; o < 320; o += 256) {
        int r2 = o / 10, c = o - r2 * 10;
        if (r2 < nrows) {
            float s = 0.f;
            #pragma unroll 16
            for (int l = 0; l < 64; l++) s += hid[r2][l] * Wb[((size_t)d * 64 + l) * 10 + c];
            outs[(size_t)rowidx[r2] * 10 + c] = s + bb[d * 10 + c];
        }
    }
}

// ---------------------------------------------------------------------------
extern "C" void kernel_launch(void* const* d_in, const int* in_sizes, int n_in,
                              void* d_out, int out_size, void* d_ws, size_t ws_size,
                              hipStream_t stream)
{
    const float* x     = (const float*)d_in[0];
    const float* W1    = (const float*)d_in[1];
    const float* b1    = (const float*)d_in[2];
    const float* gamma = (const float*)d_in[3];
    const float* beta  = (const float*)d_in[4];
    const float* Wd1   = (const float*)d_in[5];
    const float* bd1   = (const float*)d_in[6];
    const float* Wd2   = (const float*)d_in[7];
    const float* bd2   = (const float*)d_in[8];
    const float* Wa    = (const float*)d_in[9];
    const float* ba    = (const float*)d_in[10];
    const float* Wb    = (const float*)d_in[11];
    const float* bb    = (const float*)d_in[12];

    float* out    = (float*)d_out;
    float* outs   = out;
    float* outdom = out + (size_t)BATCH * 10;

    const int NT1 = 25, NT2 = 24;

    char* ws = (char*)d_ws;
    size_t off = 0;
    unsigned short* hbf = (unsigned short*)(ws + off); off += (size_t)BATCH * HD * 2;
    unsigned short* xbf = (unsigned short*)(ws + off); off += (size_t)BATCH * 800 * 2;
    unsigned short* fbf = xbf;   // alias: xbf dead after GEMM1; 768 <= 800 per row
    char*  W1hC   = ws + off;            off += (size_t)6 * NT1 * 8192;
    char*  Wd1hC  = ws + off;            off += (size_t)6 * NT2 * 8192;
    float* sp1    = (float*)(ws + off);  off += (size_t)HD * 1024 * 4;
    float* sp2    = (float*)(ws + off);  off += (size_t)HD * 1024 * 4;
    float* scale  = (float*)(ws + off);  off += HD * 4;
    float* shift  = (float*)(ws + off);  off += HD * 4;
    size_t zoff = off;
    double* domacc = (double*)(ws + off); off += (size_t)BATCH * 3 * 8;
    int*    cnt    = (int*)(ws + off);    off += 64;
    int*    fixmeta= (int*)(ws + off);    off += 64;
    size_t zbytes = off - zoff;
    int*    lists  = (int*)(ws + off);    off += (size_t)3 * BATCH * 4;
    int*    fixlist= (int*)(ws + off);    off += (size_t)BATCH * 4;

    hipMemsetAsync(ws + zoff, 0, zbytes, stream);

    tileW<<<6 * NT1, 256, 0, stream>>>(W1, W1hC, KIN, HD, NT1);
    tileW<<<6 * NT2, 256, 0, stream>>>(Wd1, Wd1hC, HD, HD, NT2);
    cvtX<<<BATCH * 100 / 256, 256, 0, stream>>>(x, xbf);

    gemm97<0><<<3072, 256, 0, stream>>>(xbf, W1hC, b1, hbf,
                                        nullptr, nullptr, sp1, sp2, 800, NT1);
    bnfinal<<<HD, 256, 0, stream>>>(sp1, sp2, gamma, beta, scale, shift);
    featBN<<<BATCH * 96 / 256, 256, 0, stream>>>(hbf, scale, shift, fbf);
    gemm97<1><<<3072, 256, 0, stream>>>(fbf, Wd1hC, bd1, nullptr,
                                        Wd2, domacc, nullptr, nullptr, HD, NT2);
    domfinal_a<<<BATCH / 256, 256, 0, stream>>>(domacc, bd2, outdom, fixmeta, fixlist);
    fixrow_x<<<512, 256, 0, stream>>>(fixmeta, fixlist, x, W1, b1, scale, shift,
                                      Wd1, bd1, Wd2, bd2, outdom);
    domfinal_b<<<BATCH / 256, 256, 0, stream>>>(outdom, cnt, lists);
    dim3 eg(BATCH / 32, 3);
    expert_kernel<<<eg, 256, 0, stream>>>(fbf, cnt, lists, Wa, ba, Wb, bb, outs);
}

// Round 16
// 716.764 us; speedup vs baseline: 1.8468x; 1.3983x over previous
//
#include <hip/hip_runtime.h>
#include <math.h>

#define BATCH 65536
#define KIN   784
#define HD    768

typedef float f32x4 __attribute__((ext_vector_type(4)));
typedef short s16x8 __attribute__((ext_vector_type(8)));
typedef unsigned int __attribute__((address_space(3))) lds_u32;
typedef const unsigned int __attribute__((address_space(1))) glb_u32;

__device__ __forceinline__ float frelu(float x){ return x > 0.f ? x : 0.f; }

// packed bf16 convert: dst = {lo16=cvt(a), hi16=cvt(b)}
__device__ __forceinline__ unsigned int cvtpk(float a, float b){
    unsigned int r;
    asm("v_cvt_pk_bf16_f32 %0, %1, %2" : "=v"(r) : "v"(a), "v"(b));
    return r;
}
__device__ __forceinline__ unsigned short f2bf(float v){
    unsigned int u = __builtin_bit_cast(unsigned int, v);
    u += 0x7FFFu + ((u >> 16) & 1u);
    return (unsigned short)(u >> 16);
}
__device__ __forceinline__ float bf2f(unsigned short s){
    unsigned int u = ((unsigned int)s) << 16;
    return __builtin_bit_cast(float, u);
}
__device__ __forceinline__ void gload16(const void* g, void* l){
    __builtin_amdgcn_global_load_lds((glb_u32*)g, (lds_u32*)l, 16, 0, 0);
}

// ---------------------------------------------------------------------------
// x [B,784] fp32 -> xbf [B,800] bf16 (pad zeroed). One uint4 (8 elems)/thread.
// ---------------------------------------------------------------------------
__global__ __launch_bounds__(256)
void cvtX(const float* __restrict__ x, unsigned short* __restrict__ xbf)
{
    int idx = blockIdx.x * 256 + threadIdx.x;     // BATCH*100 total
    int row = idx / 100, c = (idx - row * 100) * 8;
    uint4 o = make_uint4(0, 0, 0, 0);
    if (c < KIN) {
        const float* p = x + (size_t)row * KIN + c;
        float4 a = *(const float4*)p;
        float4 b = *(const float4*)(p + 4);
        o.x = cvtpk(a.x, a.y); o.y = cvtpk(a.z, a.w);
        o.z = cvtpk(b.x, b.y); o.w = cvtpk(b.z, b.w);
    }
    *(uint4*)(xbf + (size_t)row * 800 + c) = o;
}

// ---------------------------------------------------------------------------
// feat = relu(hbf*scale + shift) -> fbf (bf16). 8 elems/thread.
// ---------------------------------------------------------------------------
__global__ __launch_bounds__(256)
void featBN(const unsigned short* __restrict__ hbf,
            const float* __restrict__ scale, const float* __restrict__ shift,
            unsigned short* __restrict__ fbf)
{
    int idx = blockIdx.x * 256 + threadIdx.x;     // BATCH*96 total
    int row = idx / 96, c = (idx - row * 96) * 8;
    s16x8 hv = *(const s16x8*)(hbf + (size_t)row * HD + c);
    float4 s0 = *(const float4*)(scale + c), s1 = *(const float4*)(scale + c + 4);
    float4 t0 = *(const float4*)(shift + c), t1 = *(const float4*)(shift + c + 4);
    float v[8];
    v[0] = frelu(bf2f((unsigned short)hv[0]) * s0.x + t0.x);
    v[1] = frelu(bf2f((unsigned short)hv[1]) * s0.y + t0.y);
    v[2] = frelu(bf2f((unsigned short)hv[2]) * s0.z + t0.z);
    v[3] = frelu(bf2f((unsigned short)hv[3]) * s0.w + t0.w);
    v[4] = frelu(bf2f((unsigned short)hv[4]) * s1.x + t1.x);
    v[5] = frelu(bf2f((unsigned short)hv[5]) * s1.y + t1.y);
    v[6] = frelu(bf2f((unsigned short)hv[6]) * s1.z + t1.z);
    v[7] = frelu(bf2f((unsigned short)hv[7]) * s1.w + t1.w);
    uint4 o;
    o.x = cvtpk(v[0], v[1]); o.y = cvtpk(v[2], v[3]);
    o.z = cvtpk(v[4], v[5]); o.w = cvtpk(v[6], v[7]);
    *(uint4*)(fbf + (size_t)row * HD + c) = o;
}

// ---------------------------------------------------------------------------
// Pre-tile W[K][N] fp32 -> bf16 per-(nb,t) 8KB chunks = exact swizzled LDS
// image: byte (r*64+p*16+e*2) = bf16 of W[t*32+s*8+e][nb*128+r], s=p^((r>>1)&3)
// ---------------------------------------------------------------------------
__global__ __launch_bounds__(256)
void tileW(const float* __restrict__ W, char* __restrict__ Wh, int K, int N, int NT)
{
    int chunk = blockIdx.x;
    int nb = chunk / NT, t = chunk - nb * NT;
    int tid = threadIdx.x;
    #pragma unroll
    for (int q = 0; q < 2; q++) {
        int idx = q * 256 + tid;
        int r = idx >> 2, p = idx & 3;
        int s = (p ^ ((r >> 1) & 3)) & 3;
        int kb = t * 32 + s * 8;
        int n = nb * 128 + r;
        s16x8 hv;
        #pragma unroll
        for (int e = 0; e < 8; e++) {
            int k = kb + e;
            float v = (k < K) ? W[(size_t)k * N + n] : 0.f;
            hv[e] = (short)f2bf(v);
        }
        *(s16x8*)(Wh + (size_t)chunk * 8192 + idx * 16) = hv;
    }
}

// ---- Wa[d] 768x64 -> 24 chunks of 4KB per domain (64-row swizzled image) ---
__global__ __launch_bounds__(256)
void tileWa(const float* __restrict__ Wa, char* __restrict__ WaC)
{
    int chunk = blockIdx.x;            // d*24 + t
    int d = chunk / 24, t = chunk - d * 24;
    int idx = threadIdx.x;
    int r = idx >> 2, p = idx & 3;     // r = expert col (0..63)
    int s = (p ^ ((r >> 1) & 3)) & 3;
    int kb = t * 32 + s * 8;
    s16x8 hv;
    #pragma unroll
    for (int e = 0; e < 8; e++)
        hv[e] = (short)f2bf(Wa[((size_t)d * HD + kb + e) * 64 + r]);
    *(s16x8*)(WaC + (size_t)chunk * 4096 + idx * 16) = hv;
}

// ---------------------------------------------------------------------------
// m97-shaped bf16 GEMM: BOTH operands staged via global_load_lds (A from a
// bf16 row-major array with per-lane pre-swizzled k-offsets; B from pre-tiled
// chunks). ZERO VALU in the K-loop. Single 16KB buffer, 2-barrier loop.
// MODE 0: A=xbf(KP=800); epilogue h(bf16) + fused BN column partials.
// MODE 1: A=fbf(KP=768); epilogue a=relu(acc+bd1); domacc += a @ Wd2.
// ---------------------------------------------------------------------------
template<int MODE>
__global__ __launch_bounds__(256, 3)
void gemm97(const unsigned short* __restrict__ Abf,
            const char* __restrict__ BhC,
            const float* __restrict__ bias,
            unsigned short* __restrict__ Hbf,
            const float* __restrict__ Wd2, double* __restrict__ domacc,
            float* __restrict__ sp1, float* __restrict__ sp2,
            int KP, int NT)
{
    __shared__ __align__(16) char sm[16384];      // A 8KB | B 8KB

    int bid = blockIdx.x;
    int wg = (bid & 7) * 384 + (bid >> 3);        // XCD-contiguous remap
    int mb = wg / 6, nb = wg - mb * 6;
    int m0 = mb << 7, n0 = nb << 7;

    int tid = threadIdx.x;
    int lane = tid & 63, wid = tid >> 6;
    int wr = wid >> 1, wc = wid & 1;
    int l15 = lane & 15, l4 = lane >> 4;

    int aoff[4], boff[4];
    #pragma unroll
    for (int f = 0; f < 4; f++) {
        int ra = wr * 64 + f * 16 + l15;
        aoff[f] = ra * 64 + (((l4 ^ (ra >> 1)) & 3) << 4);
        int rb = wc * 64 + f * 16 + l15;
        boff[f] = rb * 64 + (((l4 ^ (rb >> 1)) & 3) << 4);
    }

    // staging: idx = q*256+tid -> row r, phys slot p; source k-group s
    int ar[2], asl[2];
    #pragma unroll
    for (int q = 0; q < 2; q++) {
        int idx = q * 256 + tid;
        int r = idx >> 2, p = idx & 3;
        asl[q] = (p ^ ((r >> 1) & 3)) & 3;
        ar[q] = r;
    }

    f32x4 acc[4][4];
    #pragma unroll
    for (int i = 0; i < 4; i++)
        #pragma unroll
        for (int j = 0; j < 4; j++) acc[i][j] = (f32x4){0.f, 0.f, 0.f, 0.f};

    for (int t = 0; t < NT; t++) {
        #pragma unroll
        for (int q = 0; q < 2; q++) {             // stage A (pre-swizzled source)
            const unsigned short* src = Abf + (size_t)(m0 + ar[q]) * KP + t * 32 + asl[q] * 8;
            gload16(src, sm + (q * 256 + tid) * 16);
        }
        size_t cb = (size_t)(nb * NT + t) * 8192;
        #pragma unroll
        for (int q = 0; q < 2; q++) {             // stage B (linear chunk)
            int off = (q * 256 + tid) * 16;
            gload16(BhC + cb + off, sm + 8192 + off);
        }
        __syncthreads();                          // drains vmem+lds (compiler)
        s16x8 fah[4], fbh[4];
        #pragma unroll
        for (int f = 0; f < 4; f++) {
            fah[f] = *(const s16x8*)(sm + aoff[f]);
            fbh[f] = *(const s16x8*)(sm + 8192 + boff[f]);
        }
        #pragma unroll
        for (int i = 0; i < 4; i++)
            #pragma unroll
            for (int j = 0; j < 4; j++)
                acc[i][j] = __builtin_amdgcn_mfma_f32_16x16x32_bf16(fah[i], fbh[j], acc[i][j], 0, 0, 0);
        __syncthreads();                          // readers done before restage
    }

    if (MODE == 0) {
        float bc[4];
        #pragma unroll
        for (int f = 0; f < 4; f++) bc[f] = bias[n0 + wc * 64 + f * 16 + l15];
        float cs[4] = {0.f,0.f,0.f,0.f}, cq[4] = {0.f,0.f,0.f,0.f};
        #pragma unroll
        for (int i = 0; i < 4; i++) {
            int rowb = m0 + wr * 64 + i * 16 + l4 * 4;
            #pragma unroll
            for (int j2 = 0; j2 < 4; j2++) {
                unsigned short* hrow = Hbf + (size_t)(rowb + j2) * HD + n0 + wc * 64 + l15;
                #pragma unroll
                for (int f = 0; f < 4; f++) {
                    float v = acc[i][f][j2] + bc[f];
                    hrow[f * 16] = (unsigned short)cvtpk(v, v);   // lo16 = bf16(v)
                    cs[f] += v; cq[f] += v * v;
                }
            }
        }
        #pragma unroll
        for (int m = 16; m < 64; m <<= 1)
            #pragma unroll
            for (int f = 0; f < 4; f++) {
                cs[f] += __shfl_xor(cs[f], m, 64);
                cq[f] += __shfl_xor(cq[f], m, 64);
            }
        if (l4 == 0) {
            #pragma unroll
            for (int f = 0; f < 4; f++) {
                int col = n0 + wc * 64 + f * 16 + l15;
                sp1[(size_t)col * 1024 + mb * 2 + wr] = cs[f];
                sp2[(size_t)col * 1024 + mb * 2 + wr] = cq[f];
            }
        }
    } else {
        float bc[4], w2[4][3];
        #pragma unroll
        for (int f = 0; f < 4; f++) {
            int col = n0 + wc * 64 + f * 16 + l15;
            bc[f] = bias[col];
            w2[f][0] = Wd2[col * 3 + 0]; w2[f][1] = Wd2[col * 3 + 1]; w2[f][2] = Wd2[col * 3 + 2];
        }
        float s0[16], s1[16], s2[16];
        #pragma unroll
        for (int i = 0; i < 16; i++) { s0[i] = 0.f; s1[i] = 0.f; s2[i] = 0.f; }
        #pragma unroll
        for (int i = 0; i < 4; i++)
            #pragma unroll
            for (int j2 = 0; j2 < 4; j2++) {
                int idx = i * 4 + j2;
                #pragma unroll
                for (int f = 0; f < 4; f++) {
                    float v = frelu(acc[i][f][j2] + bc[f]);
                    s0[idx] += v * w2[f][0];
                    s1[idx] += v * w2[f][1];
                    s2[idx] += v * w2[f][2];
                }
            }
        #pragma unroll
        for (int m = 1; m < 16; m <<= 1) {
            #pragma unroll
            for (int i = 0; i < 16; i++) {
                s0[i] += __shfl_xor(s0[i], m, 64);
                s1[i] += __shfl_xor(s1[i], m, 64);
                s2[i] += __shfl_xor(s2[i], m, 64);
            }
        }
        if (l15 == 0) {
            #pragma unroll
            for (int i = 0; i < 16; i++) {
                int row = m0 + wr * 64 + (i >> 2) * 16 + l4 * 4 + (i & 3);
                atomicAdd(&domacc[(size_t)row * 3 + 0], (double)s0[i]);
                atomicAdd(&domacc[(size_t)row * 3 + 1], (double)s1[i]);
                atomicAdd(&domacc[(size_t)row * 3 + 2], (double)s2[i]);
            }
        }
    }
}

// ---- BN final: reduce 1024 fp32 partials per column in fp64 ----------------
__global__ __launch_bounds__(256)
void bnfinal(const float* __restrict__ sp1, const float* __restrict__ sp2,
             const float* __restrict__ gamma, const float* __restrict__ beta,
             float* __restrict__ scale, float* __restrict__ shift)
{
    int c = blockIdx.x, t = threadIdx.x;
    const float* p1 = sp1 + (size_t)c * 1024;
    const float* p2 = sp2 + (size_t)c * 1024;
    double S = (double)p1[t] + (double)p1[t + 256] + (double)p1[t + 512] + (double)p1[t + 768];
    double Q = (double)p2[t] + (double)p2[t + 256] + (double)p2[t + 512] + (double)p2[t + 768];
    #pragma unroll
    for (int m = 1; m < 64; m <<= 1) { S += __shfl_xor(S, m, 64); Q += __shfl_xor(Q, m, 64); }
    __shared__ double sd1[4], sd2[4];
    int w = t >> 6;
    if ((t & 63) == 0) { sd1[w] = S; sd2[w] = Q; }
    __syncthreads();
    if (t == 0) {
        double Sa = sd1[0] + sd1[1] + sd1[2] + sd1[3];
        double Qa = sd2[0] + sd2[1] + sd2[2] + sd2[3];
        double mu  = Sa * (1.0 / 65536.0);
        double var = Qa * (1.0 / 65536.0) - mu * mu;
        double inv = 1.0 / sqrt(var + 1e-5);
        double sc  = inv * (double)gamma[c];
        double sh  = (double)beta[c] - mu * sc;
        scale[c] = (float)sc;
        shift[c] = (float)sh;
    }
}

// ---- dom_out finalize pass A: write outdom, flag borderline rows -----------
__global__ __launch_bounds__(256)
void domfinal_a(const double* __restrict__ domacc, const float* __restrict__ bd2,
                float* __restrict__ outdom, int* __restrict__ fixmeta, int* __restrict__ fixlist)
{
    int r = blockIdx.x * 256 + threadIdx.x;
    double v0 = domacc[(size_t)r * 3 + 0] + (double)bd2[0];
    double v1 = domacc[(size_t)r * 3 + 1] + (double)bd2[1];
    double v2 = domacc[(size_t)r * 3 + 2] + (double)bd2[2];
    outdom[(size_t)r * 3 + 0] = (float)v0;
    outdom[(size_t)r * 3 + 1] = (float)v1;
    outdom[(size_t)r * 3 + 2] = (float)v2;
    double mx01 = v0 > v1 ? v0 : v1, mn01 = v0 > v1 ? v1 : v0;
    double best = mx01 > v2 ? mx01 : v2;
    double m2   = mx01 > v2 ? (mn01 > v2 ? mn01 : v2) : mx01;
    if (best - m2 < 1.5e-2) {
        int p = atomicAdd(fixmeta, 1);
        fixlist[p] = r;
    }
}

// ---- exact recompute of dom_out for flagged rows, FROM x (fp32) ------------
// r12 version verbatim (best measured: 236us). r13/14/15 redesigns all lost.
#define FR 8
__global__ __launch_bounds__(256)
void fixrow_x(const int* __restrict__ fixmeta, const int* __restrict__ fixlist,
              const float* __restrict__ x, const float* __restrict__ W1,
              const float* __restrict__ b1,
              const float* __restrict__ scale, const float* __restrict__ shift,
              const float* __restrict__ Wd1, const float* __restrict__ bd1,
              const float* __restrict__ Wd2, const float* __restrict__ bd2,
              float* __restrict__ outdom)
{
    int nfix = fixmeta[0];
    __shared__ float xs[FR][788];
    __shared__ float ft[FR][HD];
    __shared__ float red[4][3];
    int tid = threadIdx.x;
    int n0 = tid * 3;
    for (int base = blockIdx.x * FR; base < nfix; base += gridDim.x * FR) {
        int nr = nfix - base; if (nr > FR) nr = FR;
        __syncthreads();
        for (int i = tid; i < FR * KIN; i += 256) {
            int rr = i / KIN, c = i - rr * KIN;
            int row = fixlist[base + (rr < nr ? rr : nr - 1)];
            xs[rr][c] = x[(size_t)row * KIN + c];
        }
        __syncthreads();
        {
            float acc[FR][3];
            #pragma unroll
            for (int r = 0; r < FR; r++) { acc[r][0]=0.f; acc[r][1]=0.f; acc[r][2]=0.f; }
            for (int k = 0; k < KIN; k++) {
                float w0 = W1[(size_t)k * HD + n0];
                float w1 = W1[(size_t)k * HD + n0 + 1];
                float w2 = W1[(size_t)k * HD + n0 + 2];
                #pragma unroll
                for (int r = 0; r < FR; r++) {
                    float xv = xs[r][k];
                    acc[r][0] += xv * w0; acc[r][1] += xv * w1; acc[r][2] += xv * w2;
                }
            }
            #pragma unroll
            for (int j = 0; j < 3; j++) {
                float bj = b1[n0 + j], scj = scale[n0 + j], shj = shift[n0 + j];
                #pragma unroll
                for (int r = 0; r < FR; r++)
                    ft[r][n0 + j] = frelu((acc[r][j] + bj) * scj + shj);
            }
        }
        __syncthreads();
        float acc[FR][3];
        #pragma unroll
        for (int r = 0; r < FR; r++) { acc[r][0]=0.f; acc[r][1]=0.f; acc[r][2]=0.f; }
        for (int k = 0; k < HD; k++) {
            float w0 = Wd1[(size_t)k * HD + n0];
            float w1 = Wd1[(size_t)k * HD + n0 + 1];
            float w2 = Wd1[(size_t)k * HD + n0 + 2];
            #pragma unroll
            for (int r = 0; r < FR; r++) {
                float fv = ft[r][k];
                acc[r][0] += fv * w0; acc[r][1] += fv * w1; acc[r][2] += fv * w2;
            }
        }
        float b0 = bd1[n0], b1v = bd1[n0 + 1], b2 = bd1[n0 + 2];
        float wa[3][3];
        #pragma unroll
        for (int i = 0; i < 3; i++)
            #pragma unroll
            for (int d = 0; d < 3; d++) wa[i][d] = Wd2[(n0 + i) * 3 + d];
        #pragma unroll
        for (int r = 0; r < FR; r++) {
            if (r >= nr) break;
            float h0 = frelu(acc[r][0] + b0);
            float h1 = frelu(acc[r][1] + b1v);
            float h2 = frelu(acc[r][2] + b2);
            float y0 = h0 * wa[0][0] + h1 * wa[1][0] + h2 * wa[2][0];
            float y1 = h0 * wa[0][1] + h1 * wa[1][1] + h2 * wa[2][1];
            float y2 = h0 * wa[0][2] + h1 * wa[1][2] + h2 * wa[2][2];
            #pragma unroll
            for (int m = 1; m < 64; m <<= 1) {
                y0 += __shfl_xor(y0, m, 64);
                y1 += __shfl_xor(y1, m, 64);
                y2 += __shfl_xor(y2, m, 64);
            }
            if ((tid & 63) == 0) { red[tid >> 6][0] = y0; red[tid >> 6][1] = y1; red[tid >> 6][2] = y2; }
            __syncthreads();
            if (tid == 0) {
                int row = fixlist[base + r];
                double v0 = (double)red[0][0] + red[1][0] + red[2][0] + red[3][0] + (double)bd2[0];
                double v1 = (double)red[0][1] + red[1][1] + red[2][1] + red[3][1] + (double)bd2[1];
                double v2 = (double)red[0][2] + red[1][2] + red[2][2] + red[3][2] + (double)bd2[2];
                outdom[(size_t)row * 3 + 0] = (float)v0;
                outdom[(size_t)row * 3 + 1] = (float)v1;
                outdom[(size_t)row * 3 + 2] = (float)v2;
            }
            __syncthreads();
        }
    }
}

// ---- pass B: argmax + bucket (block-aggregated atomics) --------------------
__global__ __launch_bounds__(256)
void domfinal_b(const float* __restrict__ outdom, int* __restrict__ cnt, int* __restrict__ lists)
{
    __shared__ int lcnt[3], base[3];
    int tid = threadIdx.x;
    if (tid < 3) lcnt[tid] = 0;
    __syncthreads();
    int r = blockIdx.x * 256 + tid;
    float v0 = outdom[(size_t)r * 3 + 0];
    float v1 = outdom[(size_t)r * 3 + 1];
    float v2 = outdom[(size_t)r * 3 + 2];
    int p = 0; float best = v0;
    if (v1 > best) { best = v1; p = 1; }
    if (v2 > best) { best = v2; p = 2; }
    int lpos = atomicAdd(&lcnt[p], 1);
    __syncthreads();
    if (tid < 3) base[tid] = atomicAdd(&cnt[tid], lcnt[tid]);
    __syncthreads();
    lists[(size_t)p * BATCH + base[p] + lpos] = r;
}

// ---- expert via MFMA: 128 gathered rows x 64(E) x K=768 per block ----------
// A gathered with global_load_lds (per-lane SOURCE addresses; LDS dest linear)
// B = Wa pre-tiled swizzled bf16 chunks. Same frag formulas as gemm97.
// Epilogue: hid=relu(acc+ba) -> LDS -> 64x10 mini-GEMM -> scatter to outs.
__global__ __launch_bounds__(256)
void expert_mfma(const unsigned short* __restrict__ fbf,
                 const char* __restrict__ WaC,
                 const int* __restrict__ cnt, const int* __restrict__ lists,
                 const float* __restrict__ ba,
                 const float* __restrict__ Wb, const float* __restrict__ bb,
                 float* __restrict__ outs)
{
    __shared__ __align__(16) char sm[12288];   // A 8KB | B 4KB
    __shared__ float hid[128][66];
    __shared__ int rowidx[128];

    int d = blockIdx.y;
    int count = cnt[d];
    int start = blockIdx.x * 128;
    if (start >= count) return;
    int nrows = count - start; if (nrows > 128) nrows = 128;

    int tid = threadIdx.x;
    int lane = tid & 63, wid = tid >> 6;       // 4 waves stacked on M
    int l15 = lane & 15, l4 = lane >> 4;

    if (tid < 128) {
        int i = tid < nrows ? tid : nrows - 1;
        rowidx[tid] = lists[(size_t)d * BATCH + start + i];
    }
    __syncthreads();

    // A staging: 512 groups, 2 per thread
    int asl[2], arow[2];
    #pragma unroll
    for (int q = 0; q < 2; q++) {
        int idx = q * 256 + tid;
        int r = idx >> 2, p = idx & 3;
        asl[q] = (p ^ ((r >> 1) & 3)) & 3;
        arow[q] = rowidx[r];
    }

    int aoff[2], boff[4];
    #pragma unroll
    for (int i2 = 0; i2 < 2; i2++) {
        int ra = wid * 32 + i2 * 16 + l15;
        aoff[i2] = ra * 64 + (((l4 ^ (ra >> 1)) & 3) << 4);
    }
    #pragma unroll
    for (int f = 0; f < 4; f++) {
        int rb = f * 16 + l15;
        boff[f] = rb * 64 + (((l4 ^ (rb >> 1)) & 3) << 4);
    }

    f32x4 acc[2][4];
    #pragma unroll
    for (int i = 0; i < 2; i++)
        #pragma unroll
        for (int j = 0; j < 4; j++) acc[i][j] = (f32x4){0.f, 0.f, 0.f, 0.f};

    for (int t = 0; t < 24; t++) {
        #pragma unroll
        for (int q = 0; q < 2; q++)
            gload16(fbf + (size_t)arow[q] * HD + t * 32 + asl[q] * 8,
                    sm + (q * 256 + tid) * 16);
        gload16(WaC + (size_t)(d * 24 + t) * 4096 + tid * 16, sm + 8192 + tid * 16);
        __syncthreads();
        s16x8 fa[2], fb[4];
        #pragma unroll
        for (int i2 = 0; i2 < 2; i2++) fa[i2] = *(const s16x8*)(sm + aoff[i2]);
        #pragma unroll
        for (int f = 0; f < 4; f++)    fb[f]  = *(const s16x8*)(sm + 8192 + boff[f]);
        #pragma unroll
        for (int i2 = 0; i2 < 2; i2++)
            #pragma unroll
            for (int f = 0; f < 4; f++)
                acc[i2][f] = __builtin_amdgcn_mfma_f32_16x16x32_bf16(fa[i2], fb[f], acc[i2][f], 0, 0, 0);
        __syncthreads();
    }

    #pragma unroll
    for (int i2 = 0; i2 < 2; i2++)
        #pragma unroll
        for (int f = 0; f < 4; f++) {
            int col = f * 16 + l15;
            float bav = ba[d * 64 + col];
            #pragma unroll
            for (int j = 0; j < 4; j++) {
                int row = wid * 32 + i2 * 16 + l4 * 4 + j;
                hid[row][col] = frelu(acc[i2][f][j] + bav);
            }
        }
    __syncthreads();

    for (int o = tid; o < 1280; o += 256) {
        int r2 = o / 10, c = o - r2 * 10;
        if (r2 < nrows) {
            float s = 0.f;
            #pragma unroll 16
            for (int l = 0; l < 64; l++) s += hid[r2][l] * Wb[((size_t)d * 64 + l) * 10 + c];
            outs[(size_t)rowidx[r2] * 10 + c] = s + bb[d * 10 + c];
        }
    }
}

// ---------------------------------------------------------------------------
extern "C" void kernel_launch(void* const* d_in, const int* in_sizes, int n_in,
                              void* d_out, int out_size, void* d_ws, size_t ws_size,
                              hipStream_t stream)
{
    const float* x     = (const float*)d_in[0];
    const float* W1    = (const float*)d_in[1];
    const float* b1    = (const float*)d_in[2];
    const float* gamma = (const float*)d_in[3];
    const float* beta  = (const float*)d_in[4];
    const float* Wd1   = (const float*)d_in[5];
    const float* bd1   = (const float*)d_in[6];
    const float* Wd2   = (const float*)d_in[7];
    const float* bd2   = (const float*)d_in[8];
    const float* Wa    = (const float*)d_in[9];
    const float* ba    = (const float*)d_in[10];
    const float* Wb    = (const float*)d_in[11];
    const float* bb    = (const float*)d_in[12];

    float* out    = (float*)d_out;
    float* outs   = out;
    float* outdom = out + (size_t)BATCH * 10;

    const int NT1 = 25, NT2 = 24;

    char* ws = (char*)d_ws;
    size_t off = 0;
    unsigned short* hbf = (unsigned short*)(ws + off); off += (size_t)BATCH * HD * 2;
    unsigned short* xbf = (unsigned short*)(ws + off); off += (size_t)BATCH * 800 * 2;
    unsigned short* fbf = xbf;   // alias: xbf dead after GEMM1; 768 <= 800 per row
    char*  W1hC   = ws + off;            off += (size_t)6 * NT1 * 8192;
    char*  Wd1hC  = ws + off;            off += (size_t)6 * NT2 * 8192;
    char*  WaC    = ws + off;            off += (size_t)3 * 24 * 4096;
    float* sp1    = (float*)(ws + off);  off += (size_t)HD * 1024 * 4;
    float* sp2    = (float*)(ws + off);  off += (size_t)HD * 1024 * 4;
    float* scale  = (float*)(ws + off);  off += HD * 4;
    float* shift  = (float*)(ws + off);  off += HD * 4;
    size_t zoff = off;
    double* domacc = (double*)(ws + off); off += (size_t)BATCH * 3 * 8;
    int*    cnt    = (int*)(ws + off);    off += 64;
    int*    fixmeta= (int*)(ws + off);    off += 64;
    size_t zbytes = off - zoff;
    int*    lists  = (int*)(ws + off);    off += (size_t)3 * BATCH * 4;
    int*    fixlist= (int*)(ws + off);    off += (size_t)BATCH * 4;

    hipMemsetAsync(ws + zoff, 0, zbytes, stream);

    tileW<<<6 * NT1, 256, 0, stream>>>(W1, W1hC, KIN, HD, NT1);
    tileW<<<6 * NT2, 256, 0, stream>>>(Wd1, Wd1hC, HD, HD, NT2);
    tileWa<<<72, 256, 0, stream>>>(Wa, WaC);
    cvtX<<<BATCH * 100 / 256, 256, 0, stream>>>(x, xbf);

    gemm97<0><<<3072, 256, 0, stream>>>(xbf, W1hC, b1, hbf,
                                        nullptr, nullptr, sp1, sp2, 800, NT1);
    bnfinal<<<HD, 256, 0, stream>>>(sp1, sp2, gamma, beta, scale, shift);
    featBN<<<BATCH * 96 / 256, 256, 0, stream>>>(hbf, scale, shift, fbf);
    gemm97<1><<<3072, 256, 0, stream>>>(fbf, Wd1hC, bd1, nullptr,
                                        Wd2, domacc, nullptr, nullptr, HD, NT2);
    domfinal_a<<<BATCH / 256, 256, 0, stream>>>(domacc, bd2, outdom, fixmeta, fixlist);
    fixrow_x<<<2048, 256, 0, stream>>>(fixmeta, fixlist, x, W1, b1, scale, shift,
                                       Wd1, bd1, Wd2, bd2, outdom);
    domfinal_b<<<BATCH / 256, 256, 0, stream>>>(outdom, cnt, lists);
    dim3 eg(512, 3);
    expert_mfma<<<eg, 256, 0, stream>>>(fbf, WaC, cnt, lists, ba, Wb, bb, outs);
}